// Round 1
// baseline (1847.969 us; speedup 1.0000x reference)
//
#include <hip/hip_runtime.h>
#include <hip/hip_bf16.h>
#include <stdint.h>

#define NNODES  40000
#define NEDGES  800000
#define HBITS   21
#define HSIZE   (1u << HBITS)
#define HMASK   (HSIZE - 1u)
#define EMPTYKEY 0xFFFFFFFFu

__device__ __forceinline__ unsigned hash_key(unsigned k) {
  return (k * 2654435761u) >> (32 - HBITS);
}

// broadcast lane k's value to all lanes via SGPR (1 VALU op, result uniform)
__device__ __forceinline__ float bcast(float v, int k) {
  return __int_as_float(__builtin_amdgcn_readlane(__float_as_int(v), k));
}

// Kernel 1: per-edge message MLP + segment-sum into agg + hash-table insert.
// One wave per edge; lane j computes msg[e][j]; W_msg row j register-resident.
extern "C" __global__ __launch_bounds__(256) void k_msg(
    const float* __restrict__ eh, const int* __restrict__ src,
    const int* __restrict__ tgt, const float* __restrict__ Wm,
    const float* __restrict__ bm, float* __restrict__ msg,
    float* __restrict__ agg, unsigned* __restrict__ hkeys,
    int* __restrict__ heads, int* __restrict__ nxt)
{
  const int lane = threadIdx.x & 63;
  const int wid  = (int)((blockIdx.x * blockDim.x + threadIdx.x) >> 6);
  const int nw   = (int)((gridDim.x * blockDim.x) >> 6);

  float w[64];
  {
    const float4* wr = (const float4*)(Wm + (size_t)lane * 64);
#pragma unroll
    for (int i = 0; i < 16; ++i) {
      float4 t = wr[i];
      w[4*i+0] = t.x; w[4*i+1] = t.y; w[4*i+2] = t.z; w[4*i+3] = t.w;
    }
  }
  const float bias = bm[lane];

  for (int e = wid; e < NEDGES; e += nw) {
    const float ehv = eh[(size_t)e * 64 + lane];
    float a0 = bias, a1 = 0.f, a2 = 0.f, a3 = 0.f;
#pragma unroll
    for (int k = 0; k < 64; k += 4) {
      a0 = fmaf(bcast(ehv, k+0), w[k+0], a0);
      a1 = fmaf(bcast(ehv, k+1), w[k+1], a1);
      a2 = fmaf(bcast(ehv, k+2), w[k+2], a2);
      a3 = fmaf(bcast(ehv, k+3), w[k+3], a3);
    }
    float m = (a0 + a1) + (a2 + a3);
    m = m > 0.f ? m : 0.f;
    msg[(size_t)e * 64 + lane] = m;
    const int t = tgt[e];
    atomicAdd(&agg[(size_t)t * 64 + lane], m);
    if (lane == 0) {
      const unsigned key = (unsigned)src[e] * (unsigned)NNODES + (unsigned)t;
      unsigned h = hash_key(key);
      while (true) {
        unsigned prev = atomicCAS(&hkeys[h], EMPTYKEY, key);
        if (prev == EMPTYKEY || prev == key) break;
        h = (h + 1) & HMASK;
      }
      nxt[e] = atomicExch(&heads[h], e);   // push e onto this pair's chain
    }
  }
}

// Kernel 2: exclusion gather (hash chain walk) + update MLP.
// One wave per edge; lane j computes out[e][j]; W_upd row j (144 f32) register-resident.
extern "C" __global__ __launch_bounds__(256) void k_out(
    const float* __restrict__ x, const float* __restrict__ ea,
    const float* __restrict__ Wu, const float* __restrict__ bu,
    const int* __restrict__ src, const int* __restrict__ tgt,
    const float* __restrict__ msg, const float* __restrict__ agg,
    const unsigned* __restrict__ hkeys, const int* __restrict__ heads,
    const int* __restrict__ nxt, float* __restrict__ out)
{
  const int lane = threadIdx.x & 63;
  const int wid  = (int)((blockIdx.x * blockDim.x + threadIdx.x) >> 6);
  const int nw   = (int)((gridDim.x * blockDim.x) >> 6);

  float w[144];
  {
    const float4* wr = (const float4*)(Wu + (size_t)lane * 144);
#pragma unroll
    for (int i = 0; i < 36; ++i) {
      float4 t = wr[i];
      w[4*i+0] = t.x; w[4*i+1] = t.y; w[4*i+2] = t.z; w[4*i+3] = t.w;
    }
  }
  const float bias = bu[lane];

  for (int e = wid; e < NEDGES; e += nw) {
    const int s = src[e];
    const int t = tgt[e];
    const float xv  = x[(size_t)s * 64 + lane];
    const float eav = (lane < 16) ? ea[(size_t)e * 16 + lane] : 0.f;

    // exclusion: sum of msg over all edges f with (src_f,tgt_f) == (t,s)
    const unsigned rkey = (unsigned)t * (unsigned)NNODES + (unsigned)s;
    unsigned h = hash_key(rkey);
    while (true) {
      const unsigned kk = hkeys[h];
      if (kk == rkey) break;
      if (kk == EMPTYKEY) break;   // shouldn't happen (reverse edge exists)
      h = (h + 1) & HMASK;
    }
    float excl = 0.f;
    for (int f = heads[h]; f >= 0; f = nxt[f])
      excl += msg[(size_t)f * 64 + lane];

    const float emv = agg[(size_t)s * 64 + lane] - excl;

    float a0 = bias, a1 = 0.f, a2 = 0.f, a3 = 0.f;
#pragma unroll
    for (int k = 0; k < 64; k += 4) {
      a0 = fmaf(bcast(xv, k+0), w[k+0], a0);
      a1 = fmaf(bcast(xv, k+1), w[k+1], a1);
      a2 = fmaf(bcast(xv, k+2), w[k+2], a2);
      a3 = fmaf(bcast(xv, k+3), w[k+3], a3);
    }
#pragma unroll
    for (int k = 0; k < 16; k += 4) {
      a0 = fmaf(bcast(eav, k+0), w[64+k+0], a0);
      a1 = fmaf(bcast(eav, k+1), w[64+k+1], a1);
      a2 = fmaf(bcast(eav, k+2), w[64+k+2], a2);
      a3 = fmaf(bcast(eav, k+3), w[64+k+3], a3);
    }
#pragma unroll
    for (int k = 0; k < 64; k += 4) {
      a0 = fmaf(bcast(emv, k+0), w[80+k+0], a0);
      a1 = fmaf(bcast(emv, k+1), w[80+k+1], a1);
      a2 = fmaf(bcast(emv, k+2), w[80+k+2], a2);
      a3 = fmaf(bcast(emv, k+3), w[80+k+3], a3);
    }
    float o = (a0 + a1) + (a2 + a3);
    out[(size_t)e * 64 + lane] = o > 0.f ? o : 0.f;
  }
}

extern "C" void kernel_launch(void* const* d_in, const int* in_sizes, int n_in,
                              void* d_out, int out_size, void* d_ws, size_t ws_size,
                              hipStream_t stream)
{
  const float* x  = (const float*)d_in[0];
  const float* ea = (const float*)d_in[1];
  const float* eh = (const float*)d_in[2];
  const float* Wm = (const float*)d_in[3];
  const float* bm = (const float*)d_in[4];
  const float* Wu = (const float*)d_in[5];
  const float* bu = (const float*)d_in[6];
  const int*   ei = (const int*)d_in[7];
  const int* src = ei;
  const int* tgt = ei + NEDGES;
  float* out = (float*)d_out;

  // workspace layout (all 256B aligned):
  //   msg   : E*64 f32   = 204,800,000 B @ 0
  //   agg   : N*64 f32   =  10,240,000 B @ 204,800,000
  //   hkeys : HSIZE u32  =   8,388,608 B @ 215,040,000
  //   heads : HSIZE i32  =   8,388,608 B @ 223,428,608
  //   nxt   : E i32      =   3,200,000 B @ 231,817,216   (total ~235 MB)
  char* ws = (char*)d_ws;
  float*    msg   = (float*)(ws);
  float*    agg   = (float*)(ws + 204800000);
  unsigned* hkeys = (unsigned*)(ws + 215040000);
  int*      heads = (int*)(ws + 223428608);
  int*      nxt   = (int*)(ws + 231817216);

  hipMemsetAsync(agg, 0, (size_t)NNODES * 64 * sizeof(float), stream);
  hipMemsetAsync(hkeys, 0xFF, (size_t)HSIZE * 4 * 2, stream);  // hkeys + heads (contiguous)

  dim3 blk(256);
  k_msg<<<dim3(2048), blk, 0, stream>>>(eh, src, tgt, Wm, bm, msg, agg, hkeys, heads, nxt);
  k_out<<<dim3(2048), blk, 0, stream>>>(x, ea, Wu, bu, src, tgt, msg, agg, hkeys, heads, nxt, out);
}

// Round 2
// 698.788 us; speedup vs baseline: 2.6445x; 2.6445x over previous
//
#include <hip/hip_runtime.h>
#include <hip/hip_bf16.h>
#include <stdint.h>

#define NNODES  40000
#define NEDGES  800000
#define NTILES  (NEDGES/16)
#define HBITS   21
#define HSIZE   (1u << HBITS)
#define HMASK   (HSIZE - 1u)
#define EMPTYKEY 0xFFFFFFFFu

typedef __attribute__((ext_vector_type(8))) short short8;   // bf16x8 (4 VGPRs)
typedef __attribute__((ext_vector_type(4))) float f32x4;

__device__ __forceinline__ unsigned hash_key(unsigned k) {
  return (k * 2654435761u) >> (32 - HBITS);
}
__device__ __forceinline__ ushort f2bf(float f) {
  union { __hip_bfloat16 h; ushort u; } c; c.h = __float2bfloat16(f); return c.u;
}
__device__ __forceinline__ float bf2f(ushort u) {
  return __uint_as_float((unsigned)u << 16);
}
// load 8 contiguous fp32 and convert RNE -> bf16x8
__device__ __forceinline__ short8 cvt8(const float* __restrict__ p) {
  f32x4 a = *(const f32x4*)p;
  f32x4 b = *(const f32x4*)(p + 4);
  short8 r;
  r[0] = (short)f2bf(a[0]); r[1] = (short)f2bf(a[1]);
  r[2] = (short)f2bf(a[2]); r[3] = (short)f2bf(a[3]);
  r[4] = (short)f2bf(b[0]); r[5] = (short)f2bf(b[1]);
  r[6] = (short)f2bf(b[2]); r[7] = (short)f2bf(b[3]);
  return r;
}

// Kernel 1: msg = relu(eh @ Wm^T + bm) via MFMA; store msg bf16; atomic agg; hash insert.
// One wave = 16 edges. A: eh rows, B[k][n] = Wm[n][k].
extern "C" __global__ __launch_bounds__(256) void k_msg(
    const float* __restrict__ eh, const int* __restrict__ src,
    const int* __restrict__ tgt, const float* __restrict__ Wm,
    const float* __restrict__ bm, ushort* __restrict__ msg,
    float* __restrict__ agg, unsigned* __restrict__ hkeys,
    int* __restrict__ heads, int* __restrict__ nxt)
{
  const int lane = threadIdx.x & 63;
  const int wid  = (int)((blockIdx.x * blockDim.x + threadIdx.x) >> 6);
  const int nw   = (int)((gridDim.x * blockDim.x) >> 6);
  const int m = lane & 15, oct = lane >> 4;

  short8 Bf[2][4];
#pragma unroll
  for (int kk = 0; kk < 2; ++kk)
#pragma unroll
    for (int nf = 0; nf < 4; ++nf)
      Bf[kk][nf] = cvt8(Wm + (size_t)(nf * 16 + m) * 64 + kk * 32 + oct * 8);
  float bias[4];
#pragma unroll
  for (int nf = 0; nf < 4; ++nf) bias[nf] = bm[nf * 16 + m];

  for (int t = wid; t < NTILES; t += nw) {
    const int e0 = t * 16;
    const int eA = e0 + m;
    const float* ep = eh + (size_t)eA * 64;
    short8 A0 = cvt8(ep + oct * 8);
    short8 A1 = cvt8(ep + 32 + oct * 8);
    f32x4 acc[4] = {};
#pragma unroll
    for (int nf = 0; nf < 4; ++nf) {
      acc[nf] = __builtin_amdgcn_mfma_f32_16x16x32_bf16(A0, Bf[0][nf], acc[nf], 0, 0, 0);
      acc[nf] = __builtin_amdgcn_mfma_f32_16x16x32_bf16(A1, Bf[1][nf], acc[nf], 0, 0, 0);
    }
    // D: lane holds rows oct*4+r (r=0..3), col m; ch = nf*16+m
    int tg[4];
#pragma unroll
    for (int r = 0; r < 4; ++r) tg[r] = tgt[e0 + oct * 4 + r];
#pragma unroll
    for (int nf = 0; nf < 4; ++nf) {
#pragma unroll
      for (int r = 0; r < 4; ++r) {
        float v = acc[nf][r] + bias[nf];
        v = v > 0.f ? v : 0.f;
        ushort ub = f2bf(v);
        float vb = bf2f(ub);          // rounded value, consistent with stored msg
        msg[(size_t)(e0 + oct * 4 + r) * 64 + nf * 16 + m] = ub;
        atomicAdd(&agg[(size_t)tg[r] * 64 + nf * 16 + m], vb);
      }
    }
    if (lane < 16) {
      const int e = e0 + lane;
      const unsigned key = (unsigned)src[e] * (unsigned)NNODES + (unsigned)tgt[e];
      unsigned h = hash_key(key);
      while (true) {
        unsigned prev = atomicCAS(&hkeys[h], EMPTYKEY, key);
        if (prev == EMPTYKEY || prev == key) break;
        h = (h + 1) & HMASK;
      }
      nxt[e] = atomicExch(&heads[h], e);
    }
  }
}

// Kernel 2: out = relu([x[src] | em | ea](perm) @ Wu^T(perm) + bu) via MFMA.
// K-order: [x 0..64 | em 64..128 (Wu cols 80..144) | ea 128..144 (Wu cols 64..80) | pad]
extern "C" __global__ __launch_bounds__(256) void k_out(
    const float* __restrict__ x, const float* __restrict__ ea,
    const float* __restrict__ Wu, const float* __restrict__ bu,
    const int* __restrict__ src, const int* __restrict__ tgt,
    const ushort* __restrict__ msg, const float* __restrict__ agg,
    const unsigned* __restrict__ hkeys, const int* __restrict__ heads,
    const int* __restrict__ nxt, float* __restrict__ out)
{
  const int lane = threadIdx.x & 63;
  const int wid  = (int)((blockIdx.x * blockDim.x + threadIdx.x) >> 6);
  const int nw   = (int)((gridDim.x * blockDim.x) >> 6);
  const int m = lane & 15, oct = lane >> 4;

  const short8 zero8 = {0, 0, 0, 0, 0, 0, 0, 0};
  short8 Bf[5][4];
#pragma unroll
  for (int kk = 0; kk < 5; ++kk) {
    const int k = kk * 32 + oct * 8;
    const int col = (k < 64) ? k : (k < 128 ? k + 16 : k - 64);
#pragma unroll
    for (int nf = 0; nf < 4; ++nf) {
      if (k >= 144) Bf[kk][nf] = zero8;
      else          Bf[kk][nf] = cvt8(Wu + (size_t)(nf * 16 + m) * 144 + col);
    }
  }
  float bias[4];
#pragma unroll
  for (int nf = 0; nf < 4; ++nf) bias[nf] = bu[nf * 16 + m];

  for (int t = wid; t < NTILES; t += nw) {
    const int e0 = t * 16;
    const int eA = e0 + m;
    const int s = src[eA], tt = tgt[eA];

    // exclusion windows: ch oct*8..+8 and 32+oct*8..+8
    float ex[16];
#pragma unroll
    for (int i = 0; i < 16; ++i) ex[i] = 0.f;
    {
      const unsigned rkey = (unsigned)tt * (unsigned)NNODES + (unsigned)s;
      unsigned h = hash_key(rkey);
      while (true) {
        const unsigned kk = hkeys[h];
        if (kk == rkey || kk == EMPTYKEY) break;
        h = (h + 1) & HMASK;
      }
      for (int f = heads[h]; f >= 0; f = nxt[f]) {
        const ushort* mp = msg + (size_t)f * 64;
        short8 w0 = *(const short8*)(mp + oct * 8);
        short8 w1 = *(const short8*)(mp + 32 + oct * 8);
#pragma unroll
        for (int i = 0; i < 8; ++i) {
          ex[i]     += bf2f((ushort)w0[i]);
          ex[8 + i] += bf2f((ushort)w1[i]);
        }
      }
    }

    const float* xp = x + (size_t)s * 64;
    short8 A0 = cvt8(xp + oct * 8);
    short8 A1 = cvt8(xp + 32 + oct * 8);

    const float* ap = agg + (size_t)s * 64;
    f32x4 g0 = *(const f32x4*)(ap + oct * 8);
    f32x4 g1 = *(const f32x4*)(ap + oct * 8 + 4);
    f32x4 g2 = *(const f32x4*)(ap + 32 + oct * 8);
    f32x4 g3 = *(const f32x4*)(ap + 32 + oct * 8 + 4);
    short8 A2, A3;
#pragma unroll
    for (int i = 0; i < 4; ++i) {
      A2[i]     = (short)f2bf(g0[i] - ex[i]);
      A2[4 + i] = (short)f2bf(g1[i] - ex[4 + i]);
      A3[i]     = (short)f2bf(g2[i] - ex[8 + i]);
      A3[4 + i] = (short)f2bf(g3[i] - ex[12 + i]);
    }
    short8 A4 = zero8;
    if (oct < 2) A4 = cvt8(ea + (size_t)eA * 16 + oct * 8);

    f32x4 acc[4] = {};
#pragma unroll
    for (int nf = 0; nf < 4; ++nf) {
      acc[nf] = __builtin_amdgcn_mfma_f32_16x16x32_bf16(A0, Bf[0][nf], acc[nf], 0, 0, 0);
      acc[nf] = __builtin_amdgcn_mfma_f32_16x16x32_bf16(A1, Bf[1][nf], acc[nf], 0, 0, 0);
      acc[nf] = __builtin_amdgcn_mfma_f32_16x16x32_bf16(A2, Bf[2][nf], acc[nf], 0, 0, 0);
      acc[nf] = __builtin_amdgcn_mfma_f32_16x16x32_bf16(A3, Bf[3][nf], acc[nf], 0, 0, 0);
      acc[nf] = __builtin_amdgcn_mfma_f32_16x16x32_bf16(A4, Bf[4][nf], acc[nf], 0, 0, 0);
    }
#pragma unroll
    for (int nf = 0; nf < 4; ++nf) {
#pragma unroll
      for (int r = 0; r < 4; ++r) {
        float v = acc[nf][r] + bias[nf];
        out[(size_t)(e0 + oct * 4 + r) * 64 + nf * 16 + m] = v > 0.f ? v : 0.f;
      }
    }
  }
}

extern "C" void kernel_launch(void* const* d_in, const int* in_sizes, int n_in,
                              void* d_out, int out_size, void* d_ws, size_t ws_size,
                              hipStream_t stream)
{
  const float* x  = (const float*)d_in[0];
  const float* ea = (const float*)d_in[1];
  const float* eh = (const float*)d_in[2];
  const float* Wm = (const float*)d_in[3];
  const float* bm = (const float*)d_in[4];
  const float* Wu = (const float*)d_in[5];
  const float* bu = (const float*)d_in[6];
  const int*   ei = (const int*)d_in[7];
  const int* src = ei;
  const int* tgt = ei + NEDGES;
  float* out = (float*)d_out;

  // workspace layout:
  //   msg   : E*64 bf16 = 102,400,000 B @ 0
  //   agg   : N*64 f32  =  10,240,000 B @ 102,400,000
  //   hkeys : HSIZE u32 =   8,388,608 B @ 112,640,000
  //   heads : HSIZE i32 =   8,388,608 B @ 121,028,608
  //   nxt   : E i32     =   3,200,000 B @ 129,417,216   (total ~133 MB)
  char* ws = (char*)d_ws;
  ushort*   msg   = (ushort*)(ws);
  float*    agg   = (float*)(ws + 102400000);
  unsigned* hkeys = (unsigned*)(ws + 112640000);
  int*      heads = (int*)(ws + 121028608);
  int*      nxt   = (int*)(ws + 129417216);

  hipMemsetAsync(agg, 0, (size_t)NNODES * 64 * sizeof(float), stream);
  hipMemsetAsync(hkeys, 0xFF, (size_t)HSIZE * 4 * 2, stream);  // hkeys + heads contiguous

  dim3 blk(256);
  k_msg<<<dim3(2048), blk, 0, stream>>>(eh, src, tgt, Wm, bm, msg, agg, hkeys, heads, nxt);
  k_out<<<dim3(2048), blk, 0, stream>>>(x, ea, Wu, bu, src, tgt, msg, agg, hkeys, heads, nxt, out);
}